// Round 12
// baseline (187.400 us; speedup 1.0000x reference)
//
#include <hip/hip_runtime.h>

// Problem constants (fixed in the reference file)
#define OHh   60
#define OWw   60
#define NBINS (OHh * OWw)   // 3600
#define NB    64            // batches
#define NS    4096          // spikes per batch
#define CAP   128

#define NW     4            // waves per block
#define SEG    (NS / NW)    // 1024 spikes scanned per wave
#define CH     (SEG / 64)   // 16 chunks per wave
#define HCAP   160          // hit-list cap per wave (lambda ~80, +9 sigma)
#define HBUF   176          // hitbuf entries: [0,160) hits, [n,n+12) sentinels
#define PW     5            // presence words per (wave,bin): 160 bits
#define PRE0   64           // slots [PRE0, CAP) prefilled -1 during scan
#define REPS   3            // R18 DIAGNOSTIC (resubmit -- R11 attempt died to
                            // container infra, no GPU result): 3 idempotent
                            // reps so the kernel (~120 us) lands in the top-5
                            // PMC rows. R17's issue trims converted to ZERO
                            // time (138.6 vs 138.1) -> no longer issue-bound;
                            // the R13 counters described the OLD structure.
                            // This buys the presence-scatter structure's own
                            // VALUBusy/WRITE/FETCH/Occ/bank-conflict.

// One 4-wave block per (batch, output row); lane == ow. Body = R17 verbatim
// (R15 presence-scatter + sentinel-padded phase 2, best family at 138.1).
// Rep loop: re-init pres/outimg each rep (barrier-protected), asm freshness
// on each spike register defeats cross-rep CSE (warm reps do full work).
__global__ __launch_bounds__(256) void sort_spikes_row4(
    const int* __restrict__ spikes, int* __restrict__ out) {
    const int bid  = (int)blockIdx.x;
    const int b    = bid & (NB - 1);   // batch-minor -> batch b pinned to XCD b%8
    const int row  = bid >> 6;         // output row oh, 0..59
    const int tid  = (int)threadIdx.x;
    const int wv   = tid >> 6;
    const int lane = tid & 63;
    const bool valid = lane < OWw;

    __shared__ int            hitbuf[NW][HBUF];   // 2816 B (u32 hit records)
    __shared__ unsigned       pres[NW][64][PW];   // 5120 B; stride 5 coprime 32
    __shared__ unsigned short outimg[PRE0][OWw];  // 7680 B [k][ow] staging image
    __shared__ int            cnt[NW][64];        // 1024 B
    __shared__ int            ovf;                // total ~16.6 KB -> 8 blocks/CU

    const int* __restrict__ sp   = spikes + b * NS + wv * SEG;
    int* __restrict__       outb = out + (size_t)b * (CAP * NBINS) + row * OWw;

    // Issue all 16 chunk loads FIRST (deep vmcnt pipeline; latency overlaps
    // the LDS zeroing below; L2-resident after a batch's first block).
    int vs[CH];
#pragma unroll
    for (int c = 0; c < CH; ++c) vs[c] = sp[c * 64 + lane];

    if (tid == 0) ovf = 0;
    int* const hb_w = &hitbuf[wv][0];

    for (int rep = 0; rep < REPS; ++rep) {
        // ---- Per-rep init (outimg readers finished at end-of-rep barrier).
#pragma unroll
        for (int i = 0; i < PW; ++i) pres[wv][lane][i] = 0u;  // own-wave only
        {   // outimg := all 0xFFFF; 1920 dwords across 256 threads
            int* oi = (int*)&outimg[0][0];
            for (int i = tid; i < PRE0 * OWw / 2; i += 256) oi[i] = -1;
        }

        // ---- Phase 1: collect halo hits, s-ordered, R = (w<<16) | A. ----
        int hbase = 0;
#pragma unroll
        for (int c = 0; c < CH; ++c) {
            int v = vs[c];
            asm volatile("" : "+v"(v));  // freshness: warm reps do full work
            const int h = (v >> 6) & 63;
            const int w = v & 63;
            const int A = (v >> 12) * 25 + h * 5 + w;
            const int R = (w << 16) | A;
            const bool halo = (unsigned)(h - row) < 5u;

            const unsigned long long mask = __ballot(halo);   // wave-uniform
            const int pos = __builtin_amdgcn_mbcnt_hi(
                (unsigned)(mask >> 32),
                __builtin_amdgcn_mbcnt_lo((unsigned)mask, 0));
            if (halo) hb_w[min(hbase + pos, HCAP - 1)] = R;   // s-order kept
            hbase += (int)__popcll(mask);                     // uniform

            // Hidden write: one -1 slot-row per chunk -> slots [64,128).
            if (valid) outb[(PRE0 + wv * CH + c) * NBINS + lane] = -1;
        }
        if (hbase > HCAP && lane == 0) ovf = 1;   // P ~ 1e-50
        const int n = min(hbase, HCAP);           // wave-uniform
        // Sentinels: bin = 64-kwc >= 60 for every kw lane -> self-disabling.
        if (lane < 12) hb_w[n + lane] = 64 << 16;

        // ---- Phase 2: hit-parallel presence scatter, 12 hits x 5 kw-lanes.
        const int qi  = lane / 5;                 // 0..12
        const int kwc = lane - qi * 5;            // 0..4
        for (int hbi = 0; hbi < n; hbi += 12) {   // uniform trip (~7 iters)
            const int hidx = hbi + qi;            // < HBUF
            const int R    = hb_w[hidx];          // 5-lane shared-addr read
            const int bin  = (R >> 16) - kwc;     // candidate ow
            if ((unsigned)bin < 60u)              // sentinels drop out here
                atomicOr(&pres[wv][bin][hidx >> 5], 1u << (hidx & 31));
        }

        // Own-bin count (same-wave atomics -> DS-pipe program order).
        unsigned m0 = pres[wv][lane][0], m1 = pres[wv][lane][1];
        unsigned m2 = pres[wv][lane][2], m3 = pres[wv][lane][3];
        unsigned m4 = pres[wv][lane][4];
        cnt[wv][lane] = __builtin_popcount(m0) + __builtin_popcount(m1) +
                        __builtin_popcount(m2) + __builtin_popcount(m3) +
                        __builtin_popcount(m4);
        __syncthreads();

        if (ovf == 0) {
            // ---- Phase 3: lane = bin; walk own wave's mask ascending
            //      (= s-order), scatter ck into outimg at prefix + rank. ----
            if (valid) {
                int k = 0;
                for (int w = 0; w < wv; ++w) k += cnt[w][lane];
                const int sub = row * 5 + lane;   // ck = A - 5*row - bin
                unsigned mw[PW] = {m0, m1, m2, m3, m4};
#pragma unroll
                for (int wd = 0; wd < PW; ++wd) {
                    unsigned mm = mw[wd];
                    while (mm) {                  // divergent; wall = max count
                        const int j = __builtin_ctz(mm);
                        mm &= mm - 1;
                        const int src = wd * 32 + j;
                        const int ck  = (hb_w[src] & 0xffff) - sub;
                        if (k < PRE0) outimg[k][lane] = (unsigned short)ck;
                        else if (k < CAP) outb[k * NBINS + lane] = ck; // ~1e-11
                        ++k;
                    }
                }
            }
            __syncthreads();
            // ---- Phase 4: stream outimg -> global, contiguous 240 B runs.
            if (valid) {
#pragma unroll 4
                for (int i = 0; i < PRE0 / NW; ++i) {
                    const int kk = wv * (PRE0 / NW) + i;
                    outb[kk * NBINS + lane] = (int)(short)outimg[kk][lane];
                }
            }
        } else if (wv == 0) {
            // Fallback (P ~ 1e-50): serial redo, direct global stores.
            const int* __restrict__ spf = spikes + b * NS;
            int cc = 0;
            for (int c = 0; c < NS / 64; ++c) {
                const int v = spf[c * 64 + lane];
                const int h = (v >> 6) & 63;
                unsigned long long mask = __ballot((unsigned)(h - row) < 5u);
                while (mask) {
                    const int j = (int)__builtin_ctzll(mask);
                    mask &= mask - 1;
                    const int vj = __builtin_amdgcn_readlane(
                        v, __builtin_amdgcn_readfirstlane(j));
                    const int wj  = vj & 63;
                    const int khj = ((vj >> 6) & 63) - row;
                    const int cj  = vj >> 12;
                    const int kw  = wj - lane;
                    if (((unsigned)kw < 5u) & valid) {
                        if (cc < CAP)
                            outb[cc * NBINS + lane] = cj * 25 + khj * 5 + kw;
                        ++cc;
                    }
                }
            }
            if (valid)
                for (int k = cc; k < CAP; ++k) outb[k * NBINS + lane] = -1;
        }
        __syncthreads();  // outimg/pres readers done before next rep's init
    }
}

extern "C" void kernel_launch(void* const* d_in, const int* in_sizes, int n_in,
                              void* d_out, int out_size, void* d_ws, size_t ws_size,
                              hipStream_t stream) {
    const int* spikes = (const int*)d_in[0];  // (B, S, 1, 1) int32
    // d_in[1] (indices table) unused: membership is pure arithmetic.
    int* out = (int*)d_out;                   // (B, CAP, OH, OW) int32

    dim3 grid(OHh * NB);                      // 3840 blocks, batch-minor
    dim3 block(256);                          // 4 waves/block
    sort_spikes_row4<<<grid, block, 0, stream>>>(spikes, out);
}

// Round 13
// 140.096 us; speedup vs baseline: 1.3376x; 1.3376x over previous
//
#include <hip/hip_runtime.h>

// Problem constants (fixed in the reference file)
#define OHh   60
#define OWw   60
#define NBINS (OHh * OWw)   // 3600
#define NB    64            // batches
#define NS    4096          // spikes per batch
#define CAP   128

#define NWPR   4            // waves per row (spike quarters) -- R17 granularity
#define RPB    2            // rows per block (co-timed write pairing)
#define NW     (NWPR * RPB) // 8 waves, 512 threads
#define RG     (OHh / RPB)  // 30 row-groups
#define SEG    (NS / NWPR)  // 1024 spikes scanned per wave (== R17)
#define CH     (SEG / 64)   // 16 chunks per wave
#define HCAP   160          // hit-list cap per wave (lambda ~80, +9 sigma)
#define HBUF   176          // hitbuf entries: [0,160) hits, [n,n+12) sentinels
#define PW     5            // presence words per (wave,bin): 160 bits
#define PRE0   48           // slots [PRE0, CAP) prefilled -1 before phase 2
                            // (per-bin total ~ Poisson(25); P(>48) ~ 1e-6/bin,
                            //  ~0.3 direct-store cases/launch via phase-3 path)

// R19: R18's 3-rep PMC (units FIXED: FETCH was KB -- no HBM over-fetch ever;
// R9/R13 "RMW fetch" claims were 1000x off): warm rep 26.4 us vs cold 39.6,
// VALUBusy 48%, writes 112 MB/rep at 4.2 TB/s vs 6.7 fill ceiling. Mixed
// regime: write channel idles in phases 2-3, phase-4 bursts at end, and
// ~13 us is cold partial-sector RMW (240 B runs share 64 B boundary sectors
// with the ADJACENT ROW's block, written at a different time). R19 keeps
// per-wave work byte-identical to R17 (R10/R16's mistake avoided) and only
// regroups: 8 waves = {2 adjacent rows} x {4 spike quarters}. Wave pairs
// (rsub=0,seg) and (rsub=1,seg) issue the same slot-k 240 B pieces in the
// same iterations -> L2 assembles 480 B runs; pair-interior boundary
// sectors are written by ONE block close in time (halves cold RMW) during
// BOTH prefill and phase 4. PRE0 64->48: 16 slot-rows move from the end
// burst to fire-and-forget stores before phase 2 (drain under phases 2-3).
__global__ __launch_bounds__(NW * 64) void sort_spikes_pair8(
    const int* __restrict__ spikes, int* __restrict__ out) {
    const int bid  = (int)blockIdx.x;
    const int b    = bid & (NB - 1);   // batch-minor -> batch b pinned to XCD b%8
    const int rg   = bid >> 6;         // row-group 0..29
    const int tid  = (int)threadIdx.x;
    const int wv   = tid >> 6;
    const int lane = tid & 63;
    const bool valid = lane < OWw;
    const int rsub = wv >> 2;          // which of the 2 rows this wave serves
    const int seg  = wv & 3;           // which spike quarter this wave scans
    const int row  = rg * RPB + rsub;  // output row oh

    __shared__ int            hitbuf[NW][HBUF];       // 5632 B (u32 hit records)
    __shared__ unsigned       pres[NW][64][PW];       // 10240 B; stride 5 coprime 32
    __shared__ unsigned short outimg[RPB][PRE0][OWw]; // 11520 B [row][k][ow]
    __shared__ int            cnt[RPB][NWPR][64];     // 2048 B
    __shared__ int            ovf;                    // ~29.4 KB -> 4 blk/CU
                                                      // (8 waves x4 = 32 waves/CU)

    const int* __restrict__ sp   = spikes + b * NS + seg * SEG;
    int* __restrict__       outb = out + (size_t)b * (CAP * NBINS) + row * OWw;

    // Issue all 16 chunk loads FIRST (deep vmcnt pipeline; latency overlaps
    // the LDS zeroing below; L2-resident after a batch's first block).
    int vs[CH];
#pragma unroll
    for (int c = 0; c < CH; ++c) vs[c] = sp[c * 64 + lane];

    if (tid == 0) ovf = 0;
#pragma unroll
    for (int i = 0; i < PW; ++i) pres[wv][lane][i] = 0u;  // own-wave region only
    {   // outimg := all 0xFFFF (-1); 2880 dwords across 512 threads
        int* oi = (int*)&outimg[0][0][0];
        for (int i = tid; i < RPB * PRE0 * OWw / 2; i += NW * 64) oi[i] = -1;
    }

    int* const hb_w = &hitbuf[wv][0];

    // ---- Phase 1: collect this wave's halo hits, s-ordered, as u32 records
    //      R = (w<<16) | A with A = c*25 + h*5 + w  (ck = A - 5*row - bin). ----
    int hbase = 0;
#pragma unroll
    for (int c = 0; c < CH; ++c) {
        const int v = vs[c];
        const int h = (v >> 6) & 63;
        const int w = v & 63;
        const int A = (v >> 12) * 25 + h * 5 + w;
        const int R = (w << 16) | A;
        const bool halo = (unsigned)(h - row) < 5u;

        const unsigned long long mask = __ballot(halo);   // wave-uniform
        const int pos = __builtin_amdgcn_mbcnt_hi(
            (unsigned)(mask >> 32),
            __builtin_amdgcn_mbcnt_lo((unsigned)mask, 0));
        if (halo) hb_w[min(hbase + pos, HCAP - 1)] = R;   // s-order preserved
        hbase += (int)__popcll(mask);                     // uniform

        // Prefill rows [64,128): paired waves (rsub 0/1, same seg) co-issue
        // adjacent rows' 240 B pieces -> 480 B L2-merged runs.
        if (valid) outb[(64 + seg * CH + c) * NBINS + lane] = -1;
    }
    // Prefill rows [48,64): 4 per wave, fire-and-forget; drains under
    // phases 2-3 (write channel no longer idles there).
    if (valid) {
#pragma unroll
        for (int i = 0; i < 4; ++i)
            outb[(PRE0 + seg * 4 + i) * NBINS + lane] = -1;
    }
    if (hbase > HCAP && lane == 0) ovf = 1;   // truncated list (P ~ 1e-50)
    const int n = min(hbase, HCAP);           // wave-uniform
    // Sentinels: bin = 64-kwc >= 60 for every kw lane -> self-disabling.
    if (lane < 12) hb_w[n + lane] = 64 << 16; // [n,n+12) <= [160,172) < HBUF

    // ---- Phase 2: hit-parallel presence scatter, 12 hits x 5 kw-lanes. ----
    const int qi  = lane / 5;                 // 0..12
    const int kwc = lane - qi * 5;            // 0..4
    for (int hbi = 0; hbi < n; hbi += 12) {   // uniform trip (~7 iters)
        const int hidx = hbi + qi;            // < HBUF
        const int R    = hb_w[hidx];          // 5-lane shared-addr read
        const int bin  = (R >> 16) - kwc;     // candidate ow
        if ((unsigned)bin < 60u)              // sentinels drop out here
            atomicOr(&pres[wv][bin][hidx >> 5], 1u << (hidx & 31));
    }

    // Own-bin count (same-wave atomics -> DS-pipe program order).
    unsigned m0 = pres[wv][lane][0], m1 = pres[wv][lane][1];
    unsigned m2 = pres[wv][lane][2], m3 = pres[wv][lane][3];
    unsigned m4 = pres[wv][lane][4];
    cnt[rsub][seg][lane] = __builtin_popcount(m0) + __builtin_popcount(m1) +
                           __builtin_popcount(m2) + __builtin_popcount(m3) +
                           __builtin_popcount(m4);
    __syncthreads();

    if (ovf == 0) {
        // ---- Phase 3: lane = bin; walk own wave's mask ascending (= s-order),
        //      scatter ck into outimg[rsub] at k = cross-seg prefix + rank. ----
        if (valid) {
            int k = 0;
            for (int s = 0; s < seg; ++s) k += cnt[rsub][s][lane];
            const int sub = row * 5 + lane;   // ck = A - 5*row - bin
            unsigned mw[PW] = {m0, m1, m2, m3, m4};
#pragma unroll
            for (int wd = 0; wd < PW; ++wd) {
                unsigned mm = mw[wd];
                while (mm) {                  // divergent; wall = max count
                    const int j = __builtin_ctz(mm);
                    mm &= mm - 1;
                    const int src = wd * 32 + j;
                    const int ck  = (hb_w[src] & 0xffff) - sub;
                    if (k < PRE0) outimg[rsub][k][lane] = (unsigned short)ck;
                    else if (k < CAP) outb[k * NBINS + lane] = ck;  // ~1e-6/bin;
                    ++k;  // barrier's vmcnt(0) drain ordered prefill before this
                }
            }
        }
        __syncthreads();
        // ---- Phase 4: stream outimg -> global, 12 rows per wave; paired
        //      waves co-iterate the same kk -> 480 B L2-merged runs. ----
        if (valid) {
#pragma unroll 4
            for (int i = 0; i < PRE0 / NWPR; ++i) {
                const int kk = seg * (PRE0 / NWPR) + i;
                outb[kk * NBINS + lane] = (int)(short)outimg[rsub][kk][lane];
            }
        }
    } else if (seg == 0) {
        // Fallback (P ~ 1e-50): waves (rsub,seg=0) each redo their row
        // serially over all 4096 spikes, direct global stores.
        const int* __restrict__ spf = spikes + b * NS;
        int cc = 0;
        for (int c = 0; c < NS / 64; ++c) {
            const int v = spf[c * 64 + lane];
            const int h = (v >> 6) & 63;
            unsigned long long mask = __ballot((unsigned)(h - row) < 5u);
            while (mask) {
                const int j = (int)__builtin_ctzll(mask);
                mask &= mask - 1;
                const int vj = __builtin_amdgcn_readlane(
                    v, __builtin_amdgcn_readfirstlane(j));
                const int wj  = vj & 63;
                const int khj = ((vj >> 6) & 63) - row;
                const int cj  = vj >> 12;
                const int kw  = wj - lane;
                if (((unsigned)kw < 5u) & valid) {
                    if (cc < CAP)
                        outb[cc * NBINS + lane] = cj * 25 + khj * 5 + kw;
                    ++cc;
                }
            }
        }
        if (valid)
            for (int k = cc; k < CAP; ++k) outb[k * NBINS + lane] = -1;
    }
}

extern "C" void kernel_launch(void* const* d_in, const int* in_sizes, int n_in,
                              void* d_out, int out_size, void* d_ws, size_t ws_size,
                              hipStream_t stream) {
    const int* spikes = (const int*)d_in[0];  // (B, S, 1, 1) int32
    // d_in[1] (indices table) unused: membership is pure arithmetic.
    int* out = (int*)d_out;                   // (B, CAP, OH, OW) int32

    dim3 grid(RG * NB);                       // 1920 blocks, batch-minor
    dim3 block(NW * 64);                      // 8 waves / 512 threads
    sort_spikes_pair8<<<grid, block, 0, stream>>>(spikes, out);
}

// Round 14
// 138.791 us; speedup vs baseline: 1.3502x; 1.0094x over previous
//
#include <hip/hip_runtime.h>

// Problem constants (fixed in the reference file)
#define OHh   60
#define OWw   60
#define NBINS (OHh * OWw)   // 3600
#define NB    64            // batches
#define NS    4096          // spikes per batch
#define CAP   128

#define NW     4            // waves per block
#define SEG    (NS / NW)    // 1024 spikes scanned per wave
#define CH     (SEG / 64)   // 16 chunks per wave
#define HCAP   160          // hit-list cap per wave (lambda ~80, +9 sigma; 5 mask dwords)
#define PRE0   64           // slots [PRE0, CAP) prefilled -1 during scan
                            // (per-bin total ~ Poisson(25); P(>64) ~ 1e-11)

// One 4-wave block per (batch, output row); lane == ow (lanes 60..63 parked).
// R20 = REVERT to R15 exactly (best measured: 138.089 us). Session ledger:
// R14/R15 issue cuts won while VALUBusy was 70%; at 48% (R18 PMC) further
// issue trims (R17), write-run alignment/grouping (R10/R11/R19 x3), and row
// amortization (R9/R16) all null or regress. Kernel ~39 us vs ~29 us memory
// floor; benchmark dominated by fixed fill (~70 us) + gaps (~29 us).
// Practical floor for this structure.
__global__ __launch_bounds__(256) void sort_spikes_row4(
    const int* __restrict__ spikes, int* __restrict__ out) {
    const int bid  = (int)blockIdx.x;
    const int b    = bid & (NB - 1);   // batch-minor -> batch b pinned to XCD b%8
    const int row  = bid >> 6;         // output row oh, 0..59
    const int tid  = (int)threadIdx.x;
    const int wv   = tid >> 6;
    const int lane = tid & 63;
    const bool valid = lane < OWw;

    __shared__ int            hitbuf[NW][256];    // 4096 B (u32 hit records)
    __shared__ unsigned       pres[NW][64][7];    // 7168 B (5 dwords used; stride 7
                                                  //  is coprime 32 -> bank-free)
    __shared__ unsigned short outimg[PRE0][OWw];  // 7680 B  [k][ow] staging image
    __shared__ int            cnt[NW][64];        // 1024 B
    __shared__ int            ovf;                // total ~19.5 KB -> 8 blocks/CU

    if (tid == 0) ovf = 0;
#pragma unroll
    for (int i = 0; i < 5; ++i) pres[wv][lane][i] = 0u;  // own-wave region only

    {   // outimg := all 0xFFFF (-1 rows); 1920 dwords across 256 threads
        int* oi = (int*)&outimg[0][0];
        for (int i = tid; i < PRE0 * OWw / 2; i += 256) oi[i] = -1;
    }

    const int* __restrict__ sp   = spikes + b * NS + wv * SEG;
    int* __restrict__       outb = out + (size_t)b * (CAP * NBINS) + row * OWw;

    // Issue all 16 chunk loads up front (deep vmcnt pipeline; L2-resident
    // after the first of a batch's 60 blocks touches them).
    int vs[CH];
#pragma unroll
    for (int c = 0; c < CH; ++c) vs[c] = sp[c * 64 + lane];

    int* const hb_w = &hitbuf[wv][0];
    const int row5 = row * 5;

    // ---- Phase 1: collect this wave's halo hits, s-ordered, as u32 records
    //      R = (w<<16) | A with A = ckk_base + w (so ckk(bin) = A - bin). ----
    int hbase = 0;
#pragma unroll
    for (int c = 0; c < CH; ++c) {
        const int v = vs[c];
        const int h = (v >> 6) & 63;
        const int w = v & 63;
        const int A = (v >> 12) * 25 + h * 5 + w - row5;  // >=0 for halo hits
        const int R = (w << 16) | A;
        const bool halo = (unsigned)(h - row) < 5u;

        const unsigned long long mask = __ballot(halo);   // wave-uniform
        const int pos = __builtin_amdgcn_mbcnt_hi(
            (unsigned)(mask >> 32),
            __builtin_amdgcn_mbcnt_lo((unsigned)mask, 0));
        if (halo) hb_w[min(hbase + pos, 255)] = R;        // s-order preserved
        hbase += (int)__popcll(mask);                     // uniform

        // Hidden write: one -1 slot-row per chunk -> slots [64,128) done by
        // scan end (wv*CH+c spans 0..63). Contiguous 240 B run, paced.
        if (valid) outb[(PRE0 + wv * CH + c) * NBINS + lane] = -1;
    }
    if (hbase > HCAP && lane == 0) ovf = 1;   // truncated list (P ~ 1e-50)
    const int n = min(hbase, HCAP);           // wave-uniform

    // ---- Phase 2: hit-parallel presence scatter, 12 hits x 5 kw-lanes. ----
    const int qi  = (lane < OWw) ? (lane / 5) : 4096;  // parked: hidx>=n always
    const int kwc = lane - qi * 5;
    for (int hbi = 0; hbi < n; hbi += 12) {            // uniform trip (~7 iters)
        const int hidx = hbi + qi;
        const int R    = hb_w[min(hidx, 255)];         // 5-lane shared-addr read
        const int bin  = (R >> 16) - kwc;              // this lane's candidate ow
        if (((unsigned)bin < 60u) && (hidx < n)) {     // exec-masked atomic
            atomicOr(&pres[wv][bin][hidx >> 5], 1u << (hidx & 31));
        }
    }

    // Own-bin count (atomics above are same-wave -> DS-pipe program order).
    unsigned m0 = pres[wv][lane][0], m1 = pres[wv][lane][1];
    unsigned m2 = pres[wv][lane][2], m3 = pres[wv][lane][3];
    unsigned m4 = pres[wv][lane][4];
    cnt[wv][lane] = __builtin_popcount(m0) + __builtin_popcount(m1) +
                    __builtin_popcount(m2) + __builtin_popcount(m3) +
                    __builtin_popcount(m4);
    __syncthreads();

    if (ovf == 0) {
        // ---- Phase 3: order reconstruction. lane = bin; iterate own wave's
        //      mask ascending (= s-order), scatter ckk into outimg at
        //      k = cross-wave prefix + rank. ----
        if (valid) {
            int k = 0;
            for (int w = 0; w < wv; ++w) k += cnt[w][lane];  // cross-wave prefix
            unsigned mw[5] = {m0, m1, m2, m3, m4};
#pragma unroll
            for (int wd = 0; wd < 5; ++wd) {
                unsigned mm = mw[wd];
                while (mm) {                       // divergent; wall = max count
                    const int j = __builtin_ctz(mm);
                    mm &= mm - 1;
                    const int src = wd * 32 + j;
                    const int ck  = (hb_w[src] & 0xffff) - lane;  // ckk gather
                    if (k < PRE0) outimg[k][lane] = (unsigned short)ck;
                    else if (k < CAP) outb[k * NBINS + lane] = ck;  // P ~ 1e-11
                    ++k;
                }
            }
        }
        __syncthreads();
        // ---- Phase 4: stream outimg -> global, 16 rows per wave, the proven
        //      contiguous-240B-run pattern (k-major, lane = ow). ----
        if (valid) {
#pragma unroll 4
            for (int i = 0; i < PRE0 / NW; ++i) {
                const int kk = wv * (PRE0 / NW) + i;
                outb[kk * NBINS + lane] = (int)(short)outimg[kk][lane];
            }
        }
    } else if (wv == 0) {
        // Fallback (P ~ 1e-50): serial redo, direct global stores.
        const int* __restrict__ spf = spikes + b * NS;
        int cc = 0;
        for (int c = 0; c < NS / 64; ++c) {
            const int v = spf[c * 64 + lane];
            const int h = (v >> 6) & 63;
            unsigned long long mask = __ballot((unsigned)(h - row) < 5u);
            while (mask) {
                const int j = (int)__builtin_ctzll(mask);
                mask &= mask - 1;
                const int vj =
                    __builtin_amdgcn_readlane(v, __builtin_amdgcn_readfirstlane(j));
                const int wj  = vj & 63;
                const int khj = ((vj >> 6) & 63) - row;
                const int cj  = vj >> 12;
                const int kw  = wj - lane;
                if (((unsigned)kw < 5u) & valid) {
                    if (cc < CAP)
                        outb[cc * NBINS + lane] = cj * 25 + khj * 5 + kw;
                    ++cc;
                }
            }
        }
        if (valid)
            for (int k = cc; k < CAP; ++k) outb[k * NBINS + lane] = -1;
    }
}

extern "C" void kernel_launch(void* const* d_in, const int* in_sizes, int n_in,
                              void* d_out, int out_size, void* d_ws, size_t ws_size,
                              hipStream_t stream) {
    const int* spikes = (const int*)d_in[0];  // (B, S, 1, 1) int32
    // d_in[1] (indices table) unused: membership is pure arithmetic.
    int* out = (int*)d_out;                   // (B, CAP, OH, OW) int32

    dim3 grid(OHh * NB);                      // 3840 blocks, batch-minor
    dim3 block(256);                          // 4 waves/block
    sort_spikes_row4<<<grid, block, 0, stream>>>(spikes, out);
}